// Round 4
// baseline (775.891 us; speedup 1.0000x reference)
//
#include <hip/hip_runtime.h>
#include <hip/hip_bf16.h>
#include <stdint.h>

typedef __attribute__((ext_vector_type(8))) short short8;
typedef __attribute__((ext_vector_type(4))) float floatx4;
typedef __attribute__((ext_vector_type(2))) float floatx2;

#define AS1 __attribute__((address_space(1)))
#define AS3 __attribute__((address_space(3)))

__device__ __forceinline__ void gload_lds16(const void* g, void* l) {
    __builtin_amdgcn_global_load_lds((const AS1 void*)g, (AS3 void*)l, 16, 0, 0);
}

// ---------------------------------------------------------------------------
// fp32 SGEMM: C[M,N] = A[M,K] @ B[K,N] (+bias). 128x64 tile, BK=16,
// 8x4 per thread (float2-packed: 8x2 floatx2 acc -> v_pk_fma_f32 eligible).
// Requires N % 64 == 0 (call sites: N=256, N=448). Argmin needs fp32.
//
// Occupancy is the lever: 64-col tiles give grid = (N/64)*256 blocks
// = 4+ blocks/CU = 4+ waves/SIMD (vs 2 at 128-col) to cover ds_read
// latency and barrier drains. blockIdx.x = column block (fastest-varying)
// so column-siblings sharing an A row-panel dispatch to the same XCD.
// 2-phase pipeline, zero register staging (global_load_lds for A and B).
// A stored row-major [128][16], b128-chunk XOR swizzle (chunk ^= (r>>3)&3)
// applied on the global SOURCE address and on the LDS read => conflict-free.
// ---------------------------------------------------------------------------
__global__ __launch_bounds__(256, 4) void sgemm64(
    const float* __restrict__ A, const float* __restrict__ B,
    const float* __restrict__ bias, float* __restrict__ C,
    int M, int N, int K) {
    __shared__ float sA[2][128 * 16];   // [r][k], k-chunks XOR-swizzled per row
    __shared__ float sB[2][16 * 64];    // [k][n]
    const int t = threadIdx.x;
    const int w = t >> 6;
    const int tx = t & 15, ty = t >> 4;
    const int aty = ty & 3;              // A-read swizzle key
    const long row0 = (long)blockIdx.y * 128;
    const int col0 = blockIdx.x * 64;

    // A staging: round j (j=0,1): row r = j*64 + (t>>2), chunk (t&3) (16B)
    const int rA = t >> 2;
    const int cA = (t & 3) << 2;
    const int sw = ((rA >> 3) & 3) << 2;   // same key for r and r+64
    // B staging: one round: k = t>>4, n = (t&15)*4  (dest byte = t*16, linear)
    const int kB = t >> 4;
    const int nB = (t & 15) << 2;
    const size_t wchunk = (size_t)w * 1024;  // wave-uniform LDS chunk (bytes)

    floatx2 acc[8][2];
#pragma unroll
    for (int i = 0; i < 8; i++) {
        acc[i][0] = (floatx2){0.f, 0.f};
        acc[i][1] = (floatx2){0.f, 0.f};
    }

    const int T = K >> 4;
    const int arow = ty * 8;   // first of this thread's 8 A rows

#define STAGE(buf, kk)                                                        \
    do {                                                                      \
        gload_lds16(A + (row0 + rA) * (long)K + (kk) + (cA ^ sw),             \
                    (char*)&sA[buf][0] + wchunk);                             \
        gload_lds16(A + (row0 + rA + 64) * (long)K + (kk) + (cA ^ sw),        \
                    (char*)&sA[buf][0] + 4096 + wchunk);                      \
        gload_lds16(B + (long)((kk) + kB) * N + col0 + nB,                    \
                    (char*)&sB[buf][0] + wchunk);                             \
    } while (0)

    STAGE(0, 0);
    __syncthreads();

    for (int tt = 0; tt < T; tt++) {
        const int cur = tt & 1;
        if (tt + 1 < T) {
            const int kk = (tt + 1) << 4;
            STAGE(cur ^ 1, kk);
        }
        const float* __restrict__ a = &sA[cur][0];
        const float* __restrict__ b = &sB[cur][0];
#pragma unroll
        for (int k4 = 0; k4 < 4; k4++) {
            floatx4 xa4[8];
#pragma unroll
            for (int i = 0; i < 8; i++)
                xa4[i] = *(const floatx4*)(a + (arow + i) * 16 + ((k4 ^ aty) << 2));
#pragma unroll
            for (int kq = 0; kq < 4; kq++) {
                const int k = k4 * 4 + kq;
                floatx4 y = *(const floatx4*)(b + k * 64 + tx * 4);
                floatx2 y01 = {y[0], y[1]};
                floatx2 y23 = {y[2], y[3]};
#pragma unroll
                for (int i = 0; i < 8; i++) {
                    const float av = xa4[i][kq];
                    floatx2 a2 = {av, av};
                    acc[i][0] += a2 * y01;   // -> v_pk_fma_f32 (fp contract)
                    acc[i][1] += a2 * y23;
                }
            }
        }
        __syncthreads();
    }
#undef STAGE

#pragma unroll
    for (int i = 0; i < 8; i++) {
        long gr = row0 + ty * 8 + i;
        int gc = col0 + tx * 4;
        floatx4 o = {acc[i][0][0], acc[i][0][1], acc[i][1][0], acc[i][1][1]};
        if (bias) o += *(const floatx4*)(bias + gc);
        *(floatx4*)(C + gr * N + gc) = o;
    }
}

// ---------------------------------------------------------------------------
// bf16 MFMA GEMM for the output projection (precision non-critical):
// C_f32[M,N] = A_bf16[M,K] @ Bt_bf16[N,K]^T + bias_f32. 128x128 tile, BK=64.
// ---------------------------------------------------------------------------
__global__ __launch_bounds__(256) void gemm_bt(
    const __hip_bfloat16* __restrict__ A, const __hip_bfloat16* __restrict__ Bt,
    const float* __restrict__ bias, float* __restrict__ C,
    int M, int N, int K) {
    __shared__ __hip_bfloat16 sA[128 * 64];
    __shared__ __hip_bfloat16 sB[128 * 64];
    const int t = threadIdx.x;
    const int lane = t & 63, w = t >> 6;
    const int wr = w >> 1, wc = w & 1;
    const int m16 = lane & 15, q = lane >> 4;
    const long row0 = (long)blockIdx.x * 128;
    const long col0 = (long)blockIdx.y * 128;
    const int wbase = w * 64;

    floatx4 acc[4][4];
#pragma unroll
    for (int i = 0; i < 4; i++)
#pragma unroll
        for (int j = 0; j < 4; j++) acc[i][j] = (floatx4){0.f, 0.f, 0.f, 0.f};

    for (int kk = 0; kk < K; kk += 64) {
        __syncthreads();
#pragma unroll
        for (int i = 0; i < 4; i++) {
            int li = i * 256 + t;
            int r = li >> 3, c = li & 7;
            int sc = (c ^ (r & 7)) << 3;
            gload_lds16(A + (row0 + r) * (long)K + kk + sc,
                        (char*)sA + (size_t)(i * 256 + wbase) * 16);
            gload_lds16(Bt + (col0 + r) * (long)K + kk + sc,
                        (char*)sB + (size_t)(i * 256 + wbase) * 16);
        }
        __syncthreads();
#pragma unroll
        for (int s = 0; s < 2; s++) {
            short8 af[4], bf[4];
#pragma unroll
            for (int i = 0; i < 4; i++) {
                int ra = wr * 64 + i * 16 + m16;
                int cq = s * 4 + q;
                af[i] = *(const short8*)((const char*)sA + (size_t)(ra * 8 + (cq ^ (ra & 7))) * 16);
                int rb = wc * 64 + i * 16 + m16;
                bf[i] = *(const short8*)((const char*)sB + (size_t)(rb * 8 + (cq ^ (rb & 7))) * 16);
            }
#pragma unroll
            for (int i = 0; i < 4; i++)
#pragma unroll
                for (int j = 0; j < 4; j++)
                    acc[i][j] = __builtin_amdgcn_mfma_f32_16x16x32_bf16(af[i], bf[j], acc[i][j], 0, 0, 0);
        }
    }
#pragma unroll
    for (int i = 0; i < 4; i++) {
#pragma unroll
        for (int j = 0; j < 4; j++) {
#pragma unroll
            for (int r = 0; r < 4; r++) {
                long gr = row0 + wr * 64 + i * 16 + q * 4 + r;
                long gc = col0 + wc * 64 + j * 16 + m16;
                C[gr * N + gc] = acc[i][j][r] + bias[gc];
            }
        }
    }
}

// ---------------------------------------------------------------------------
// setup kernels (fp32 inputs)
// ---------------------------------------------------------------------------
__global__ __launch_bounds__(256) void setup_ect(
    const float* __restrict__ e0, const float* __restrict__ e1,
    const float* __restrict__ e2, float* __restrict__ EcT,
    float* __restrict__ esq) {
    int n = blockIdx.x;  // 0..447
    int p = threadIdx.x; // 0..255
    const float* src = (n < 64) ? e0 + n * 256
                     : (n < 192) ? e1 + (n - 64) * 256
                                 : e2 + (n - 192) * 256;
    float v = src[p];
    EcT[p * 448 + n] = v;  // EcT[k=p][n]
    float s = v * v;
    for (int off = 32; off; off >>= 1) s += __shfl_xor(s, off);
    __shared__ float ps[4];
    if ((p & 63) == 0) ps[p >> 6] = s;
    __syncthreads();
    if (p == 0) esq[n] = ps[0] + ps[1] + ps[2] + ps[3];
}

__global__ __launch_bounds__(256) void wout_transpose(
    const float* __restrict__ W_out, __hip_bfloat16* __restrict__ WoutT) {
    int c = blockIdx.x;   // 0..1407
    int r = threadIdx.x;  // 0..255
    WoutT[(long)c * 256 + r] = __float2bfloat16(W_out[(long)r * 1408 + c]);
}

__global__ __launch_bounds__(256) void gram_kernel(
    const float* __restrict__ e0, const float* __restrict__ e1,
    const float* __restrict__ e2, float* __restrict__ G01,
    float* __restrict__ G02, float* __restrict__ G12) {
    int id = blockIdx.x * 256 + threadIdx.x;  // 57344 total
    const float *a, *b;
    float* dst;
    if (id < 8192)       { a = e0 + (id >> 7) * 256;  b = e1 + (id & 127) * 256;  dst = G01 + id; }
    else if (id < 24576) { int p = id - 8192;  a = e0 + (p >> 8) * 256; b = e2 + (p & 255) * 256; dst = G02 + p; }
    else                 { int p = id - 24576; a = e1 + (p >> 8) * 256; b = e2 + (p & 255) * 256; dst = G12 + p; }
    float s = 0.f;
    for (int j = 0; j < 256; j += 4) {
        floatx4 av = *(const floatx4*)(a + j);
        floatx4 bv = *(const floatx4*)(b + j);
        s += av[0] * bv[0] + av[1] * bv[1] + av[2] * bv[2] + av[3] * bv[3];
    }
    *dst = s;
}

// ---------------------------------------------------------------------------
// VQ: one wave per row; xor-shuffle argmin with first-index tie-break.
// Gram trick: r_l . e_k = S[k] - sum of gram corrections; ||r_l||^2 = d_{l-1}.
// ---------------------------------------------------------------------------
__device__ __forceinline__ void argmin_reduce(float& d, int& k) {
#pragma unroll
    for (int off = 32; off; off >>= 1) {
        float od = __shfl_xor(d, off);
        int ok = __shfl_xor(k, off);
        if (od < d || (od == d && ok < k)) { d = od; k = ok; }
    }
}

__global__ __launch_bounds__(256) void vq_kernel(
    const float* __restrict__ Zp, const float* __restrict__ S,
    const float* __restrict__ esq, const float* __restrict__ G01,
    const float* __restrict__ G02, const float* __restrict__ G12,
    const float* __restrict__ e0, const float* __restrict__ e1,
    const float* __restrict__ e2, __hip_bfloat16* __restrict__ zq,
    float* __restrict__ out_idx, float* __restrict__ part) {
    const int t = threadIdx.x;
    const int lane = t & 63, w = t >> 6;
    const long row = (long)blockIdx.x * 4 + w;
    const float* Srow = S + row * 448;

    floatx4 zv = *(const floatx4*)(Zp + row * 256 + lane * 4);
    float rsq = zv[0] * zv[0] + zv[1] * zv[1] + zv[2] * zv[2] + zv[3] * zv[3];
    for (int off = 32; off; off >>= 1) rsq += __shfl_xor(rsq, off);

    // level 0 (K=64)
    float d = rsq - 2.0f * Srow[lane] + esq[lane];
    int bi = lane;
    argmin_reduce(d, bi);
    const float d0 = d; const int i0 = bi;

    // level 1 (K=128)
    {
        float da = d0 - 2.0f * (Srow[64 + lane] - G01[i0 * 128 + lane]) + esq[64 + lane];
        float db = d0 - 2.0f * (Srow[128 + lane] - G01[i0 * 128 + 64 + lane]) + esq[128 + lane];
        d = da; bi = lane;
        if (db < da) { d = db; bi = lane + 64; }
        argmin_reduce(d, bi);
    }
    const float d1 = d; const int i1 = bi;

    // level 2 (K=256)
    {
        d = 1e30f; bi = 0;
#pragma unroll
        for (int jj = 0; jj < 4; jj++) {
            int k = jj * 64 + lane;
            float dd = d1 - 2.0f * (Srow[192 + k] - G02[i0 * 256 + k] - G12[i1 * 256 + k]) + esq[192 + k];
            if (dd < d) { d = dd; bi = k; }
        }
        argmin_reduce(d, bi);
    }
    const float d2 = d; const int i2 = bi;

    if (lane == 0) part[row] = d0 + d1 + d2;

    floatx4 a0 = *(const floatx4*)(e0 + i0 * 256 + lane * 4);
    floatx4 a1 = *(const floatx4*)(e1 + i1 * 256 + lane * 4);
    floatx4 a2 = *(const floatx4*)(e2 + i2 * 256 + lane * 4);
    short sv[4];
#pragma unroll
    for (int i = 0; i < 4; i++) {
        union { __hip_bfloat16 h; short s; } x;
        x.h = __float2bfloat16(a0[i] + a1[i] + a2[i]);
        sv[i] = x.s;
    }
    typedef __attribute__((ext_vector_type(4))) short short4v;
    short4v ov = {sv[0], sv[1], sv[2], sv[3]};
    *(short4v*)(zq + row * 256 + lane * 4) = ov;

    if (lane == 0) {
        out_idx[row] = (float)i0;
        out_idx[32768 + row] = (float)i1;
        out_idx[65536 + row] = (float)i2;
    }
}

__global__ __launch_bounds__(256) void finalize_loss(
    const float* __restrict__ part, float* __restrict__ out_loss) {
    int t = threadIdx.x;
    float s = 0.f;
    for (int i = t; i < 32768; i += 256) s += part[i];
    for (int off = 32; off; off >>= 1) s += __shfl_xor(s, off);
    __shared__ float ps[4];
    if ((t & 63) == 0) ps[t >> 6] = s;
    __syncthreads();
    if (t == 0)
        out_loss[0] = (ps[0] + ps[1] + ps[2] + ps[3]) * (0.25f / (8388608.0f * 3.0f));
}

// ---------------------------------------------------------------------------
extern "C" void kernel_launch(void* const* d_in, const int* in_sizes, int n_in,
                              void* d_out, int out_size, void* d_ws, size_t ws_size,
                              hipStream_t stream) {
    const float* z     = (const float*)d_in[0];
    const float* W_in  = (const float*)d_in[1];
    const float* b_in  = (const float*)d_in[2];
    const float* W_out = (const float*)d_in[3];
    const float* b_out = (const float*)d_in[4];
    const float* e0    = (const float*)d_in[5];
    const float* e1    = (const float*)d_in[6];
    const float* e2    = (const float*)d_in[7];
    float* out = (float*)d_out;

    char* ws = (char*)d_ws;
    float*          Zp    = (float*)ws;                        // 33,554,432 B
    float*          S     = (float*)(ws + 33554432);           // 58,720,256 B
    __hip_bfloat16* Zq    = (__hip_bfloat16*)(ws + 92274688);  // 16,777,216 B
    __hip_bfloat16* WoutT = (__hip_bfloat16*)(ws + 109051904); //    720,896 B
    float*          EcT   = (float*)(ws + 109772800);          //    458,752 B
    float*          esq   = (float*)(ws + 110231552);          //      1,792 B
    float*          G01   = (float*)(ws + 110233344);          //     32,768 B
    float*          G02   = (float*)(ws + 110266112);          //     65,536 B
    float*          G12   = (float*)(ws + 110331648);          //    131,072 B
    float*          part  = (float*)(ws + 110462720);          //    131,072 B

    setup_ect<<<448, 256, 0, stream>>>(e0, e1, e2, EcT, esq);
    gram_kernel<<<224, 256, 0, stream>>>(e0, e1, e2, G01, G02, G12);
    wout_transpose<<<1408, 256, 0, stream>>>(W_out, WoutT);

    // z_proj = z @ W_in + b_in  (fp32, precision-critical for argmin)
    sgemm64<<<dim3(4, 256), 256, 0, stream>>>(z, W_in, b_in, Zp, 32768, 256, 1408);
    // S = z_proj @ EcT  (fp32)
    sgemm64<<<dim3(7, 256), 256, 0, stream>>>(Zp, EcT, nullptr, S, 32768, 448, 256);
    // VQ: indices (fp32), zq (bf16), per-row loss partials
    vq_kernel<<<8192, 256, 0, stream>>>(Zp, S, esq, G01, G02, G12, e0, e1, e2,
                                        Zq, out + 46137344, part);
    // z_q_out = zq @ W_out + b_out  (bf16 MFMA, fp32 out; threshold is loose)
    gemm_bt<<<dim3(256, 11), 256, 0, stream>>>(Zq, WoutT, b_out, out, 32768, 1408, 256);
    finalize_loss<<<1, 256, 0, stream>>>(part, out + 46235648);
}

// Round 5
// 532.166 us; speedup vs baseline: 1.4580x; 1.4580x over previous
//
#include <hip/hip_runtime.h>
#include <hip/hip_bf16.h>
#include <stdint.h>

typedef __attribute__((ext_vector_type(8))) short short8;
typedef __attribute__((ext_vector_type(4))) float floatx4;
typedef _Float16 half8 __attribute__((ext_vector_type(8)));

#define AS1 __attribute__((address_space(1)))
#define AS3 __attribute__((address_space(3)))

__device__ __forceinline__ void gload_lds16(const void* g, void* l) {
    __builtin_amdgcn_global_load_lds((const AS1 void*)g, (AS3 void*)l, 16, 0, 0);
}

// ---------------------------------------------------------------------------
// fp32-accurate GEMM via fp16 2-way split + 3-product MFMA:
//   C[M,N] = A[M,K](fp32) @ Bt[N,K]^T (+bias), computed as
//   Ah*Bh + Al*Bh + Ah*Bl with a = ah + al (f16 hi/lo, 11+11 mantissa bits).
// Per-term error ~2^-22|ab| -- same class as fp32 reordered summation, so
// VQ argmin indices are preserved (plain bf16 was NOT safe; this is).
// A is split on the fly during LDS staging (fp32 global -> cvt -> ds_write);
// Bt comes pre-split (tiny). 128x128 tile, BK=64, gemm_bt slot-XOR layout.
// 96 MFMA : 32 ds_read per wave per K-tile (m97-class economics).
// Bt must have >= ceil(N/128)*128 rows (pad rows zero). Col-guarded store.
// ---------------------------------------------------------------------------
__global__ __launch_bounds__(256, 2) void mgemm(
    const float* __restrict__ A, const _Float16* __restrict__ BtHi,
    const _Float16* __restrict__ BtLo, const float* __restrict__ bias,
    float* __restrict__ C, int M, int N, int K) {
    __shared__ _Float16 sAh[128 * 64];
    __shared__ _Float16 sAl[128 * 64];
    __shared__ _Float16 sBh[128 * 64];
    __shared__ _Float16 sBl[128 * 64];
    const int t = threadIdx.x;
    const int lane = t & 63, w = t >> 6;
    const int wr = w >> 1, wc = w & 1;
    const int m16 = lane & 15, q = lane >> 4;
    const long row0 = (long)blockIdx.y * 128;   // y = row tile (x fastest ->
    const long col0 = (long)blockIdx.x * 128;   // col-siblings adjacent, L2 reuse of A)
    const int wbase = w * 64;

    floatx4 acc[4][4];
#pragma unroll
    for (int i = 0; i < 4; i++)
#pragma unroll
        for (int j = 0; j < 4; j++) acc[i][j] = (floatx4){0.f, 0.f, 0.f, 0.f};

    const int rT = t >> 3;        // A-stage row within round-block (0..31)
    const int cT = t & 7;         // A-stage chunk (8 f16 = 16B)

    for (int kk = 0; kk < K; kk += 64) {
        // A fp32 loads to regs -- issued before the sync, overlap prev compute
        floatx4 a0[4], a1[4];
#pragma unroll
        for (int i = 0; i < 4; i++) {
            const int r = i * 32 + rT;
            const float* p = A + (row0 + r) * (long)K + kk + ((cT ^ (r & 7)) << 3);
            a0[i] = *(const floatx4*)p;
            a1[i] = *(const floatx4*)(p + 4);
        }
        __syncthreads();   // previous compute done reading LDS
        // B staging: async global->LDS from pre-split arrays (slot-XOR layout)
#pragma unroll
        for (int i = 0; i < 4; i++) {
            const int li = i * 256 + t;
            const int r = li >> 3, c = li & 7;
            const int sc = (c ^ (r & 7)) << 3;
            gload_lds16(BtHi + (col0 + r) * (long)K + kk + sc,
                        (char*)sBh + (size_t)(i * 256 + wbase) * 16);
            gload_lds16(BtLo + (col0 + r) * (long)K + kk + sc,
                        (char*)sBl + (size_t)(i * 256 + wbase) * 16);
        }
        // A split + LDS write: slot (r,c) holds global k-chunk c^(r&7)
#pragma unroll
        for (int i = 0; i < 4; i++) {
            const int r = i * 32 + rT;
            half8 h, l;
#pragma unroll
            for (int j = 0; j < 4; j++) {
                _Float16 h0 = (_Float16)a0[i][j];
                h[j] = h0;
                l[j] = (_Float16)(a0[i][j] - (float)h0);
                _Float16 h1 = (_Float16)a1[i][j];
                h[4 + j] = h1;
                l[4 + j] = (_Float16)(a1[i][j] - (float)h1);
            }
            const size_t ob = (size_t)(r * 8 + cT) * 16;
            *(half8*)((char*)sAh + ob) = h;
            *(half8*)((char*)sAl + ob) = l;
        }
        __syncthreads();   // drains gload_lds (vmcnt) + ds_writes
        // compute: 2 k-subtiles x 16 (i,j) x 3 products
#pragma unroll
        for (int s = 0; s < 2; s++) {
            half8 ah[4], al[4], bh[4], bl[4];
#pragma unroll
            for (int i = 0; i < 4; i++) {
                const int ra = wr * 64 + i * 16 + m16;
                const int cq = s * 4 + q;
                const size_t oa = (size_t)(ra * 8 + (cq ^ (ra & 7))) * 16;
                ah[i] = *(const half8*)((const char*)sAh + oa);
                al[i] = *(const half8*)((const char*)sAl + oa);
                const int rb = wc * 64 + i * 16 + m16;
                const size_t ob = (size_t)(rb * 8 + (cq ^ (rb & 7))) * 16;
                bh[i] = *(const half8*)((const char*)sBh + ob);
                bl[i] = *(const half8*)((const char*)sBl + ob);
            }
#pragma unroll
            for (int i = 0; i < 4; i++)
#pragma unroll
                for (int j = 0; j < 4; j++) {
                    acc[i][j] = __builtin_amdgcn_mfma_f32_16x16x32_f16(ah[i], bh[j], acc[i][j], 0, 0, 0);
                    acc[i][j] = __builtin_amdgcn_mfma_f32_16x16x32_f16(al[i], bh[j], acc[i][j], 0, 0, 0);
                    acc[i][j] = __builtin_amdgcn_mfma_f32_16x16x32_f16(ah[i], bl[j], acc[i][j], 0, 0, 0);
                }
        }
    }
#pragma unroll
    for (int i = 0; i < 4; i++) {
#pragma unroll
        for (int j = 0; j < 4; j++) {
#pragma unroll
            for (int r4 = 0; r4 < 4; r4++) {
                long gr = row0 + wr * 64 + i * 16 + q * 4 + r4;
                int gc = (int)col0 + wc * 64 + j * 16 + m16;
                if (gc < N)
                    C[gr * (long)N + gc] = acc[i][j][r4] + (bias ? bias[gc] : 0.f);
            }
        }
    }
}

// ---------------------------------------------------------------------------
// bf16 MFMA GEMM for the output projection (precision non-critical):
// C_f32[M,N] = A_bf16[M,K] @ Bt_bf16[N,K]^T + bias_f32. 128x128 tile, BK=64.
// ---------------------------------------------------------------------------
__global__ __launch_bounds__(256) void gemm_bt(
    const __hip_bfloat16* __restrict__ A, const __hip_bfloat16* __restrict__ Bt,
    const float* __restrict__ bias, float* __restrict__ C,
    int M, int N, int K) {
    __shared__ __hip_bfloat16 sA[128 * 64];
    __shared__ __hip_bfloat16 sB[128 * 64];
    const int t = threadIdx.x;
    const int lane = t & 63, w = t >> 6;
    const int wr = w >> 1, wc = w & 1;
    const int m16 = lane & 15, q = lane >> 4;
    const long row0 = (long)blockIdx.x * 128;
    const long col0 = (long)blockIdx.y * 128;
    const int wbase = w * 64;

    floatx4 acc[4][4];
#pragma unroll
    for (int i = 0; i < 4; i++)
#pragma unroll
        for (int j = 0; j < 4; j++) acc[i][j] = (floatx4){0.f, 0.f, 0.f, 0.f};

    for (int kk = 0; kk < K; kk += 64) {
        __syncthreads();
#pragma unroll
        for (int i = 0; i < 4; i++) {
            int li = i * 256 + t;
            int r = li >> 3, c = li & 7;
            int sc = (c ^ (r & 7)) << 3;
            gload_lds16(A + (row0 + r) * (long)K + kk + sc,
                        (char*)sA + (size_t)(i * 256 + wbase) * 16);
            gload_lds16(Bt + (col0 + r) * (long)K + kk + sc,
                        (char*)sB + (size_t)(i * 256 + wbase) * 16);
        }
        __syncthreads();
#pragma unroll
        for (int s = 0; s < 2; s++) {
            short8 af[4], bf[4];
#pragma unroll
            for (int i = 0; i < 4; i++) {
                int ra = wr * 64 + i * 16 + m16;
                int cq = s * 4 + q;
                af[i] = *(const short8*)((const char*)sA + (size_t)(ra * 8 + (cq ^ (ra & 7))) * 16);
                int rb = wc * 64 + i * 16 + m16;
                bf[i] = *(const short8*)((const char*)sB + (size_t)(rb * 8 + (cq ^ (rb & 7))) * 16);
            }
#pragma unroll
            for (int i = 0; i < 4; i++)
#pragma unroll
                for (int j = 0; j < 4; j++)
                    acc[i][j] = __builtin_amdgcn_mfma_f32_16x16x32_bf16(af[i], bf[j], acc[i][j], 0, 0, 0);
        }
    }
#pragma unroll
    for (int i = 0; i < 4; i++) {
#pragma unroll
        for (int j = 0; j < 4; j++) {
#pragma unroll
            for (int r = 0; r < 4; r++) {
                long gr = row0 + wr * 64 + i * 16 + q * 4 + r;
                long gc = col0 + wc * 64 + j * 16 + m16;
                C[gr * N + gc] = acc[i][j][r] + bias[gc];
            }
        }
    }
}

// ---------------------------------------------------------------------------
// setup kernels
// ---------------------------------------------------------------------------
// Codebook split: cb_hi/lo[512][256] f16 (rows 448..511 zero) + esq[448].
__global__ __launch_bounds__(256) void setup_cb(
    const float* __restrict__ e0, const float* __restrict__ e1,
    const float* __restrict__ e2, _Float16* __restrict__ cbHi,
    _Float16* __restrict__ cbLo, float* __restrict__ esq) {
    int n = blockIdx.x;  // 0..511
    int p = threadIdx.x; // 0..255
    float v = 0.f;
    if (n < 64)       v = e0[n * 256 + p];
    else if (n < 192) v = e1[(n - 64) * 256 + p];
    else if (n < 448) v = e2[(n - 192) * 256 + p];
    _Float16 h = (_Float16)v;
    cbHi[n * 256 + p] = h;
    cbLo[n * 256 + p] = (_Float16)(v - (float)h);
    if (n < 448) {
        float s = v * v;
        for (int off = 32; off; off >>= 1) s += __shfl_xor(s, off);
        __shared__ float ps[4];
        if ((p & 63) == 0) ps[p >> 6] = s;
        __syncthreads();
        if (p == 0) esq[n] = ps[0] + ps[1] + ps[2] + ps[3];
    }
}

// W_in [1408][256] -> WinT_hi/lo [256][1408] f16 (transpose + split).
__global__ __launch_bounds__(256) void split_win(
    const float* __restrict__ W_in, _Float16* __restrict__ wHi,
    _Float16* __restrict__ wLo) {
    int p = blockIdx.x;   // 0..255 (output row = input col)
    for (int k = threadIdx.x; k < 1408; k += 256) {
        float v = W_in[(long)k * 256 + p];
        _Float16 h = (_Float16)v;
        wHi[(long)p * 1408 + k] = h;
        wLo[(long)p * 1408 + k] = (_Float16)(v - (float)h);
    }
}

__global__ __launch_bounds__(256) void wout_transpose(
    const float* __restrict__ W_out, __hip_bfloat16* __restrict__ WoutT) {
    int c = blockIdx.x;   // 0..1407
    int r = threadIdx.x;  // 0..255
    WoutT[(long)c * 256 + r] = __float2bfloat16(W_out[(long)r * 1408 + c]);
}

__global__ __launch_bounds__(256) void gram_kernel(
    const float* __restrict__ e0, const float* __restrict__ e1,
    const float* __restrict__ e2, float* __restrict__ G01,
    float* __restrict__ G02, float* __restrict__ G12) {
    int id = blockIdx.x * 256 + threadIdx.x;  // 57344 total
    const float *a, *b;
    float* dst;
    if (id < 8192)       { a = e0 + (id >> 7) * 256;  b = e1 + (id & 127) * 256;  dst = G01 + id; }
    else if (id < 24576) { int p = id - 8192;  a = e0 + (p >> 8) * 256; b = e2 + (p & 255) * 256; dst = G02 + p; }
    else                 { int p = id - 24576; a = e1 + (p >> 8) * 256; b = e2 + (p & 255) * 256; dst = G12 + p; }
    float s = 0.f;
    for (int j = 0; j < 256; j += 4) {
        floatx4 av = *(const floatx4*)(a + j);
        floatx4 bv = *(const floatx4*)(b + j);
        s += av[0] * bv[0] + av[1] * bv[1] + av[2] * bv[2] + av[3] * bv[3];
    }
    *dst = s;
}

// ---------------------------------------------------------------------------
// VQ: one wave per row; xor-shuffle argmin with first-index tie-break.
// Gram trick: r_l . e_k = S[k] - sum of gram corrections; ||r_l||^2 = d_{l-1}.
// ---------------------------------------------------------------------------
__device__ __forceinline__ void argmin_reduce(float& d, int& k) {
#pragma unroll
    for (int off = 32; off; off >>= 1) {
        float od = __shfl_xor(d, off);
        int ok = __shfl_xor(k, off);
        if (od < d || (od == d && ok < k)) { d = od; k = ok; }
    }
}

__global__ __launch_bounds__(256) void vq_kernel(
    const float* __restrict__ Zp, const float* __restrict__ S,
    const float* __restrict__ esq, const float* __restrict__ G01,
    const float* __restrict__ G02, const float* __restrict__ G12,
    const float* __restrict__ e0, const float* __restrict__ e1,
    const float* __restrict__ e2, __hip_bfloat16* __restrict__ zq,
    float* __restrict__ out_idx, float* __restrict__ part) {
    const int t = threadIdx.x;
    const int lane = t & 63, w = t >> 6;
    const long row = (long)blockIdx.x * 4 + w;
    const float* Srow = S + row * 448;

    floatx4 zv = *(const floatx4*)(Zp + row * 256 + lane * 4);
    float rsq = zv[0] * zv[0] + zv[1] * zv[1] + zv[2] * zv[2] + zv[3] * zv[3];
    for (int off = 32; off; off >>= 1) rsq += __shfl_xor(rsq, off);

    // level 0 (K=64)
    float d = rsq - 2.0f * Srow[lane] + esq[lane];
    int bi = lane;
    argmin_reduce(d, bi);
    const float d0 = d; const int i0 = bi;

    // level 1 (K=128)
    {
        float da = d0 - 2.0f * (Srow[64 + lane] - G01[i0 * 128 + lane]) + esq[64 + lane];
        float db = d0 - 2.0f * (Srow[128 + lane] - G01[i0 * 128 + 64 + lane]) + esq[128 + lane];
        d = da; bi = lane;
        if (db < da) { d = db; bi = lane + 64; }
        argmin_reduce(d, bi);
    }
    const float d1 = d; const int i1 = bi;

    // level 2 (K=256)
    {
        d = 1e30f; bi = 0;
#pragma unroll
        for (int jj = 0; jj < 4; jj++) {
            int k = jj * 64 + lane;
            float dd = d1 - 2.0f * (Srow[192 + k] - G02[i0 * 256 + k] - G12[i1 * 256 + k]) + esq[192 + k];
            if (dd < d) { d = dd; bi = k; }
        }
        argmin_reduce(d, bi);
    }
    const float d2 = d; const int i2 = bi;

    if (lane == 0) part[row] = d0 + d1 + d2;

    floatx4 a0 = *(const floatx4*)(e0 + i0 * 256 + lane * 4);
    floatx4 a1 = *(const floatx4*)(e1 + i1 * 256 + lane * 4);
    floatx4 a2 = *(const floatx4*)(e2 + i2 * 256 + lane * 4);
    short sv[4];
#pragma unroll
    for (int i = 0; i < 4; i++) {
        union { __hip_bfloat16 h; short s; } x;
        x.h = __float2bfloat16(a0[i] + a1[i] + a2[i]);
        sv[i] = x.s;
    }
    typedef __attribute__((ext_vector_type(4))) short short4v;
    short4v ov = {sv[0], sv[1], sv[2], sv[3]};
    *(short4v*)(zq + row * 256 + lane * 4) = ov;

    if (lane == 0) {
        out_idx[row] = (float)i0;
        out_idx[32768 + row] = (float)i1;
        out_idx[65536 + row] = (float)i2;
    }
}

__global__ __launch_bounds__(256) void finalize_loss(
    const float* __restrict__ part, float* __restrict__ out_loss) {
    int t = threadIdx.x;
    float s = 0.f;
    for (int i = t; i < 32768; i += 256) s += part[i];
    for (int off = 32; off; off >>= 1) s += __shfl_xor(s, off);
    __shared__ float ps[4];
    if ((t & 63) == 0) ps[t >> 6] = s;
    __syncthreads();
    if (t == 0)
        out_loss[0] = (ps[0] + ps[1] + ps[2] + ps[3]) * (0.25f / (8388608.0f * 3.0f));
}

// ---------------------------------------------------------------------------
extern "C" void kernel_launch(void* const* d_in, const int* in_sizes, int n_in,
                              void* d_out, int out_size, void* d_ws, size_t ws_size,
                              hipStream_t stream) {
    const float* z     = (const float*)d_in[0];
    const float* W_in  = (const float*)d_in[1];
    const float* b_in  = (const float*)d_in[2];
    const float* W_out = (const float*)d_in[3];
    const float* b_out = (const float*)d_in[4];
    const float* e0    = (const float*)d_in[5];
    const float* e1    = (const float*)d_in[6];
    const float* e2    = (const float*)d_in[7];
    float* out = (float*)d_out;

    char* ws = (char*)d_ws;
    float*          Zp    = (float*)ws;                        // 33,554,432 B
    float*          S     = (float*)(ws + 33554432);           // 58,720,256 B
    __hip_bfloat16* Zq    = (__hip_bfloat16*)(ws + 92274688);  // 16,777,216 B
    // Split arrays live INSIDE the Zq region: they are only needed by the
    // two mgemm calls, which complete before vq_kernel writes Zq.
    _Float16*       WinTh = (_Float16*)(ws + 92274688);        //    720,896 B
    _Float16*       WinTl = (_Float16*)(ws + 92995584);        //    720,896 B
    _Float16*       cbHi  = (_Float16*)(ws + 93716480);        //    262,144 B
    _Float16*       cbLo  = (_Float16*)(ws + 93978624);        //    262,144 B
    __hip_bfloat16* WoutT = (__hip_bfloat16*)(ws + 109051904); //    720,896 B
    float*          esq   = (float*)(ws + 110231552);          //      1,792 B
    float*          G01   = (float*)(ws + 110233344);          //     32,768 B
    float*          G02   = (float*)(ws + 110266112);          //     65,536 B
    float*          G12   = (float*)(ws + 110331648);          //    131,072 B
    float*          part  = (float*)(ws + 110462720);          //    131,072 B

    setup_cb<<<512, 256, 0, stream>>>(e0, e1, e2, cbHi, cbLo, esq);
    split_win<<<256, 256, 0, stream>>>(W_in, WinTh, WinTl);
    gram_kernel<<<224, 256, 0, stream>>>(e0, e1, e2, G01, G02, G12);
    wout_transpose<<<1408, 256, 0, stream>>>(W_out, WoutT);

    // z_proj = z @ W_in + b_in  (f16-split 3-product MFMA, fp32-class accuracy)
    mgemm<<<dim3(2, 256), 256, 0, stream>>>(z, WinTh, WinTl, b_in, Zp,
                                            32768, 256, 1408);
    // S = z_proj @ codebooks^T  (same kernel; last col-tile guarded, cb padded)
    mgemm<<<dim3(4, 256), 256, 0, stream>>>(Zp, cbHi, cbLo, nullptr, S,
                                            32768, 448, 256);
    // VQ: indices (fp32), zq (bf16), per-row loss partials
    vq_kernel<<<8192, 256, 0, stream>>>(Zp, S, esq, G01, G02, G12, e0, e1, e2,
                                        Zq, out + 46137344, part);
    // z_q_out = zq @ W_out + b_out  (bf16 MFMA, fp32 out; threshold is loose)
    gemm_bt<<<dim3(256, 11), 256, 0, stream>>>(Zq, WoutT, b_out, out, 32768, 1408, 256);
    finalize_loss<<<1, 256, 0, stream>>>(part, out + 46235648);
}